// Round 3
// baseline (163.769 us; speedup 1.0000x reference)
//
#include <hip/hip_runtime.h>
#include <stdint.h>

#define C   32
#define H   160
#define W   160
#define NB  32
#define HW  (H * W)          // 25600
#define CHW (C * HW)         // 819200
#define NPIX (NB * HW)       // 819200
#define TH  8                // tile rows per block
#define NTILES (H / TH)      // 20
#define NTHR (TH * W / 2)    // 640 threads: 2 px per thread

// d_ws layout (uint32 units):
// [0,288)    w3bits  [oc*9 + kh*3 + kw], bit ic = (w3<0)
// [288,320)  w1bits  [oc], bit ic = (w1<0)
// [320,352)  scale3 (f32)   [352,384) shift3
// [384,416)  scale1 (f32)   [416,448) shift1

__global__ void pack_params(const float* __restrict__ w3,
                            const float* __restrict__ g3, const float* __restrict__ b3,
                            const float* __restrict__ m3, const float* __restrict__ v3,
                            const float* __restrict__ w1,
                            const float* __restrict__ g1, const float* __restrict__ b1,
                            const float* __restrict__ m1, const float* __restrict__ v1,
                            uint32_t* __restrict__ wsu) {
    int t = threadIdx.x;
    if (t < 288) {
        int oc = t / 9, tap = t % 9;
        uint32_t bits = 0;
#pragma unroll
        for (int ic = 0; ic < 32; ++ic)
            bits |= (w3[oc * 288 + ic * 9 + tap] < 0.0f) ? (1u << ic) : 0u;
        wsu[t] = bits;
    } else if (t < 320) {
        int oc = t - 288;
        uint32_t bits = 0;
#pragma unroll
        for (int ic = 0; ic < 32; ++ic)
            bits |= (w1[oc * 32 + ic] < 0.0f) ? (1u << ic) : 0u;
        wsu[288 + oc] = bits;
        float* f = (float*)wsu;
        float inv3 = g3[oc] * rsqrtf(v3[oc] + 1e-5f);
        f[320 + oc] = inv3;
        f[352 + oc] = b3[oc] - m3[oc] * inv3;
        float inv1 = g1[oc] * rsqrtf(v1[oc] + 1e-5f);
        f[384 + oc] = inv1;
        f[416 + oc] = b1[oc] - m1[oc] * inv1;
    }
}

// One block = 8 rows x 160 cols of one image. Phase 1: pack sign bits for the
// 10 halo rows (clamped at image top/bottom) into LDS. Phase 2: branch-free
// interior XNOR conv3x3 + BN + residual + 1x1 block, 2 px/thread.
// Border pixels (h==0/159, w==0/159) come out wrong here (clamped halo) and
// are overwritten by border_fix afterwards.
__global__ __launch_bounds__(NTHR) void fused_tile(const float* __restrict__ x,
                                                   const uint32_t* __restrict__ wsu,
                                                   float* __restrict__ out) {
    __shared__ uint32_t sbits[(TH + 2) * W];   // 6.4 KB
    const float* wf = (const float*)wsu;
    int bid  = blockIdx.x;
    int n    = bid / NTILES;
    int tile = bid % NTILES;
    int h0   = tile * TH;
    const float* xn = x + n * CHW;
    int t = threadIdx.x;

    // ---- phase 1: bit-pack (TH+2)*W positions, 4 per active thread ----
    if (t < (TH + 2) * W / 4) {                // 400 active threads
        int prow = t / (W / 4);                // 0..9
        int qcol = (t % (W / 4)) * 4;
        int hh = h0 - 1 + prow;
        hh = (hh < 0) ? 0 : (hh > H - 1 ? H - 1 : hh);
        const float* xp = xn + hh * W + qcol;
        uint32_t b0 = 0, b1 = 0, b2 = 0, b3 = 0;
#pragma unroll
        for (int c = 0; c < 32; ++c) {
            float4 v = *reinterpret_cast<const float4*>(xp + c * HW);
            b0 |= (v.x < 0.0f) ? (1u << c) : 0u;
            b1 |= (v.y < 0.0f) ? (1u << c) : 0u;
            b2 |= (v.z < 0.0f) ? (1u << c) : 0u;
            b3 |= (v.w < 0.0f) ? (1u << c) : 0u;
        }
        *reinterpret_cast<uint4*>(&sbits[t * 4]) = make_uint4(b0, b1, b2, b3);
    }
    __syncthreads();

    // ---- phase 2: conv + BN + residual + 1x1 block, 2 px/thread ----
    int r = t / (W / 2);                       // 0..7 (tile-local row)
    int w = (t % (W / 2)) * 2;                 // even col
    int h = h0 + r;

    int wm1 = (w > 0) ? w - 1 : 0;
    int wp2 = (w < W - 2) ? w + 2 : W - 1;

    uint32_t nb[3][4];
#pragma unroll
    for (int dr = 0; dr < 3; ++dr) {
        const uint32_t* rp = &sbits[(r + dr) * W];
        nb[dr][0] = rp[wm1]; nb[dr][1] = rp[w];
        nb[dr][2] = rp[w + 1]; nb[dr][3] = rp[wp2];
    }

    const float* xrow = xn + h * W + w;
    float y0[32], y1[32];
#pragma unroll
    for (int oc = 0; oc < 32; ++oc) {
        int s0 = 0, s1 = 0;
#pragma unroll
        for (int dr = 0; dr < 3; ++dr) {
#pragma unroll
            for (int c = 0; c < 3; ++c) {
                uint32_t wv = wsu[oc * 9 + dr * 3 + c];   // uniform -> s_load
                s0 += __popc(nb[dr][c] ^ wv);
                s1 += __popc(nb[dr][c + 1] ^ wv);
            }
        }
        float sc = wf[320 + oc], sh = wf[352 + oc];
        float2 xv = *reinterpret_cast<const float2*>(xrow + oc * HW);
        y0[oc] = fmaf((float)(288 - 2 * s0), sc, sh) + xv.x;
        y1[oc] = fmaf((float)(288 - 2 * s1), sc, sh) + xv.y;
    }

    uint32_t yb0 = 0, yb1 = 0;
#pragma unroll
    for (int oc = 0; oc < 32; ++oc) {
        yb0 |= (y0[oc] < 0.0f) ? (1u << oc) : 0u;
        yb1 |= (y1[oc] < 0.0f) ? (1u << oc) : 0u;
    }
    float* orow = out + n * CHW + h * W + w;
#pragma unroll
    for (int oc = 0; oc < 32; ++oc) {
        float sc = wf[384 + oc], sh = wf[416 + oc];
        int c0 = 32 - 2 * __popc(yb0 ^ wsu[288 + oc]);
        int c1 = 32 - 2 * __popc(yb1 ^ wsu[288 + oc]);
        float2 zv;
        zv.x = fmaf((float)c0, sc, sh) + y0[oc];
        zv.y = fmaf((float)c1, sc, sh) + y1[oc];
        *reinterpret_cast<float2*>(orow + oc * HW) = zv;
    }
}

// Recompute border pixels exactly (true zero padding), bits taken straight
// from x (L2/L3-hot). 636 border px per image * 32 images = 20352 threads.
__global__ __launch_bounds__(256) void border_fix(const float* __restrict__ x,
                                                  const uint32_t* __restrict__ wsu,
                                                  float* __restrict__ out) {
    const float* wf = (const float*)wsu;
    int t = blockIdx.x * blockDim.x + threadIdx.x;
    if (t >= NB * 636) return;
    int n = t / 636, idx = t % 636;
    int h, w;
    if (idx < 160)      { h = 0;         w = idx; }
    else if (idx < 320) { h = H - 1;     w = idx - 160; }
    else if (idx < 478) { h = idx - 319; w = 0; }       // h = 1..158
    else                { h = idx - 477; w = W - 1; }   // h = 1..158

    const float* xn = x + n * CHW;
    uint32_t nb[3][3];
    int m[3][3];
#pragma unroll
    for (int r = 0; r < 3; ++r) {
        int hh = h + r - 1;
        bool rok = (hh >= 0) && (hh < H);
#pragma unroll
        for (int c = 0; c < 3; ++c) {
            int ww = w + c - 1;
            bool ok = rok && (ww >= 0) && (ww < W);
            m[r][c] = ok ? -1 : 0;
            uint32_t bits = 0;
            if (ok) {
                const float* xp = xn + hh * W + ww;
#pragma unroll
                for (int ch = 0; ch < 32; ++ch)
                    bits |= (xp[ch * HW] < 0.0f) ? (1u << ch) : 0u;
            }
            nb[r][c] = bits;
        }
    }

    const float* xp = xn + h * W + w;
    float y[32];
    uint32_t yb = 0;
#pragma unroll
    for (int oc = 0; oc < 32; ++oc) {
        int s = 0;
#pragma unroll
        for (int r = 0; r < 3; ++r) {
#pragma unroll
            for (int c = 0; c < 3; ++c) {
                uint32_t wv = wsu[oc * 9 + r * 3 + c];
                s += (32 - 2 * __popc(nb[r][c] ^ wv)) & m[r][c];
            }
        }
        float sc = wf[320 + oc], sh = wf[352 + oc];
        y[oc] = fmaf((float)s, sc, sh) + xp[oc * HW];
        yb |= (y[oc] < 0.0f) ? (1u << oc) : 0u;
    }
    float* op = out + n * CHW + h * W + w;
#pragma unroll
    for (int oc = 0; oc < 32; ++oc) {
        float sc = wf[384 + oc], sh = wf[416 + oc];
        int cc = 32 - 2 * __popc(yb ^ wsu[288 + oc]);
        op[oc * HW] = fmaf((float)cc, sc, sh) + y[oc];
    }
}

extern "C" void kernel_launch(void* const* d_in, const int* in_sizes, int n_in,
                              void* d_out, int out_size, void* d_ws, size_t ws_size,
                              hipStream_t stream) {
    const float* x  = (const float*)d_in[0];
    const float* w3 = (const float*)d_in[1];
    const float* g3 = (const float*)d_in[2];
    const float* b3 = (const float*)d_in[3];
    const float* m3 = (const float*)d_in[4];
    const float* v3 = (const float*)d_in[5];
    const float* w1 = (const float*)d_in[6];
    const float* g1 = (const float*)d_in[7];
    const float* b1 = (const float*)d_in[8];
    const float* m1 = (const float*)d_in[9];
    const float* v1 = (const float*)d_in[10];
    float* out = (float*)d_out;
    uint32_t* wsu = (uint32_t*)d_ws;

    pack_params<<<1, 320, 0, stream>>>(w3, g3, b3, m3, v3, w1, g1, b1, m1, v1, wsu);
    fused_tile<<<NB * NTILES, NTHR, 0, stream>>>(x, wsu, out);
    border_fix<<<(NB * 636 + 255) / 256, 256, 0, stream>>>(x, wsu, out);
}